// Round 1
// baseline (565.147 us; speedup 1.0000x reference)
//
#include <hip/hip_runtime.h>

static constexpr int NB = 8;
static constexpr int NS = 4096;
static constexpr int NH = 16;
static constexpr int ND = 128;
static constexpr int BH = NB * NH;      // 128
static constexpr int HD = NH * ND;      // 2048

// ---------------------------------------------------------------------------
// Kernel 1: partial unnormalized context + partial k-softmax denominator.
// grid = BH * NC blocks, 256 threads. Each block: one (b,h) and one S-chunk.
// Output per block: pctx[128][128] (sum_s exp(k[s,d]) * v[s,e]), pden[128].
// ---------------------------------------------------------------------------
template <int NC>
__global__ __launch_bounds__(256, 2)
void ctx_partial(const float* __restrict__ kk, const float* __restrict__ vv,
                 float* __restrict__ pctx, float* __restrict__ pden) {
    const int blk = blockIdx.x;
    const int bh  = blk / NC;
    const int c   = blk % NC;
    const int b   = bh >> 4;          // / NH
    const int h   = bh & 15;
    const int tid = threadIdx.x;
    constexpr int SC = NS / NC;

    __shared__ float ke[8][128];
    __shared__ float vs[8][128];

    const size_t base = (size_t)b * NS * HD + (size_t)h * ND;
    const int srow = tid >> 5;          // 0..7 staging row
    const int scol = (tid & 31) << 2;   // 0..124 step 4
    const int dg   = (tid >> 4) << 3;   // d-tile base (0..120 step 8)
    const int eg   = (tid & 15) << 3;   // e-tile base

    float acc[8][8];
#pragma unroll
    for (int i = 0; i < 8; ++i)
#pragma unroll
        for (int j = 0; j < 8; ++j) acc[i][j] = 0.f;
    float dp0 = 0.f, dp1 = 0.f, dp2 = 0.f, dp3 = 0.f;

    const float* kptr = kk + base + (size_t)(c * SC + srow) * HD + scol;
    const float* vptr = vv + base + (size_t)(c * SC + srow) * HD + scol;

    for (int st = 0; st < SC; st += 8) {
        float4 k4 = *(const float4*)kptr;
        float4 v4 = *(const float4*)vptr;
        kptr += (size_t)8 * HD;
        vptr += (size_t)8 * HD;
        float4 e4;
        e4.x = __expf(k4.x); e4.y = __expf(k4.y);
        e4.z = __expf(k4.z); e4.w = __expf(k4.w);
        dp0 += e4.x; dp1 += e4.y; dp2 += e4.z; dp3 += e4.w;
        __syncthreads();                     // prev tile consumed
        *(float4*)&ke[srow][scol] = e4;
        *(float4*)&vs[srow][scol] = v4;
        __syncthreads();                     // tile visible
#pragma unroll
        for (int ss = 0; ss < 8; ++ss) {
            float a[8], bb[8];
            *(float4*)&a[0]  = *(const float4*)&ke[ss][dg];
            *(float4*)&a[4]  = *(const float4*)&ke[ss][dg + 4];
            *(float4*)&bb[0] = *(const float4*)&vs[ss][eg];
            *(float4*)&bb[4] = *(const float4*)&vs[ss][eg + 4];
#pragma unroll
            for (int i = 0; i < 8; ++i)
#pragma unroll
                for (int j = 0; j < 8; ++j)
                    acc[i][j] = fmaf(a[i], bb[j], acc[i][j]);
        }
    }

    // write partial context (unnormalized)
    float* po = pctx + (size_t)blk * (ND * ND);
#pragma unroll
    for (int i = 0; i < 8; ++i) {
        *(float4*)&po[(dg + i) * ND + eg] =
            make_float4(acc[i][0], acc[i][1], acc[i][2], acc[i][3]);
        *(float4*)&po[(dg + i) * ND + eg + 4] =
            make_float4(acc[i][4], acc[i][5], acc[i][6], acc[i][7]);
    }

    // deterministic denominator reduction (reuse ke)
    __syncthreads();
    ke[srow][scol]     = dp0;
    ke[srow][scol + 1] = dp1;
    ke[srow][scol + 2] = dp2;
    ke[srow][scol + 3] = dp3;
    __syncthreads();
    if (tid < 128) {
        float s = 0.f;
#pragma unroll
        for (int r = 0; r < 8; ++r) s += ke[r][tid];
        pden[(size_t)blk * ND + tid] = s;
    }
}

// ---------------------------------------------------------------------------
// Kernel 2: combine chunk partials -> normalized context ctx[bh][d][e]
// ---------------------------------------------------------------------------
__global__ void ctx_combine(const float* __restrict__ pctx,
                            const float* __restrict__ pden,
                            float* __restrict__ ctx, int nc) {
    const int idx = blockIdx.x * 256 + threadIdx.x;  // < BH*ND*ND
    const int bh = idx >> 14;
    const int de = idx & 16383;
    const int d  = de >> 7;
    float s = 0.f, den = 0.f;
    for (int c = 0; c < nc; ++c) {
        s   += pctx[((size_t)(bh * nc + c) << 14) + de];
        den += pden[(size_t)(bh * nc + c) * ND + d];
    }
    ctx[idx] = s / den;
}

// ---------------------------------------------------------------------------
// Kernel 3: out[b,s,h,e] = softmax_d(q[b,s,h,:]) @ ctx[b,h,:,:]
// grid = BH * 8 blocks, 512 threads. ctx staged fully in LDS (64 KB).
// Per iteration: 64 q-rows staged+exp'd, denom via 8-lane shfl reduce,
// per-thread 4 rows x 4 cols register GEMV tile.
// ---------------------------------------------------------------------------
__global__ __launch_bounds__(512, 2)
void out_kernel(const float* __restrict__ qq, const float* __restrict__ ctx,
                float* __restrict__ out) {
    constexpr int SCH = 8;              // S-chunks per (b,h)
    const int blk = blockIdx.x;
    const int bh  = blk / SCH;
    const int c   = blk % SCH;
    const int b   = bh >> 4;
    const int h   = bh & 15;
    const int tid = threadIdx.x;

    __shared__ float cs[128 * 128];     // 64 KB context
    __shared__ float eq[64][132];       // 64 q-rows: exp(q), col 128 = row denom

    // stage ctx: 4096 float4, 512 threads -> 8 each, coalesced
    {
        const float4* src = (const float4*)(ctx + ((size_t)bh << 14));
        float4* dst = (float4*)cs;
#pragma unroll
        for (int l = 0; l < 8; ++l) dst[l * 512 + tid] = src[l * 512 + tid];
    }
    __syncthreads();

    const int rg4  = (tid >> 5) << 2;   // row-tile base 0..60 step 4
    const int eg4  = (tid & 31) << 2;   // e base 0..124 step 4
    const int lrow = tid >> 3;          // loader row 0..63
    const int lcol = (tid & 7) << 4;    // loader col base 0..112 step 16

    const size_t qbase = (size_t)b * NS * HD + (size_t)h * ND;
    const int s_base = c * (NS / SCH);  // 512 rows per block

    for (int it = 0; it < (NS / SCH) / 64; ++it) {
        // ---- stage 64 rows of q: exp + row-sum ----
        const int srow = s_base + it * 64 + lrow;
        const float* qrow = qq + qbase + (size_t)srow * HD + lcol;
        float4 a0 = *(const float4*)(qrow);
        float4 a1 = *(const float4*)(qrow + 4);
        float4 a2 = *(const float4*)(qrow + 8);
        float4 a3 = *(const float4*)(qrow + 12);
        a0.x = __expf(a0.x); a0.y = __expf(a0.y); a0.z = __expf(a0.z); a0.w = __expf(a0.w);
        a1.x = __expf(a1.x); a1.y = __expf(a1.y); a1.z = __expf(a1.z); a1.w = __expf(a1.w);
        a2.x = __expf(a2.x); a2.y = __expf(a2.y); a2.z = __expf(a2.z); a2.w = __expf(a2.w);
        a3.x = __expf(a3.x); a3.y = __expf(a3.y); a3.z = __expf(a3.z); a3.w = __expf(a3.w);
        float ps = a0.x + a0.y + a0.z + a0.w + a1.x + a1.y + a1.z + a1.w +
                   a2.x + a2.y + a2.z + a2.w + a3.x + a3.y + a3.z + a3.w;
        ps += __shfl_xor(ps, 1);
        ps += __shfl_xor(ps, 2);
        ps += __shfl_xor(ps, 4);        // all 8 loader lanes of a row hold the sum

        __syncthreads();                // previous iteration consumed eq
        *(float4*)&eq[lrow][lcol]      = a0;
        *(float4*)&eq[lrow][lcol + 4]  = a1;
        *(float4*)&eq[lrow][lcol + 8]  = a2;
        *(float4*)&eq[lrow][lcol + 12] = a3;
        if ((tid & 7) == 0) eq[lrow][128] = ps;
        __syncthreads();

        // ---- GEMV tile: acc[r][e] = sum_d eq[row][d] * ctx[d][e] ----
        float4 acc[4];
#pragma unroll
        for (int r = 0; r < 4; ++r) acc[r] = make_float4(0.f, 0.f, 0.f, 0.f);

#pragma unroll 4
        for (int db = 0; db < 32; ++db) {
            const float4 cx0 = *(const float4*)&cs[(db * 4 + 0) * 128 + eg4];
            const float4 cx1 = *(const float4*)&cs[(db * 4 + 1) * 128 + eg4];
            const float4 cx2 = *(const float4*)&cs[(db * 4 + 2) * 128 + eg4];
            const float4 cx3 = *(const float4*)&cs[(db * 4 + 3) * 128 + eg4];
#pragma unroll
            for (int r = 0; r < 4; ++r) {
                const float4 ev = *(const float4*)&eq[rg4 + r][db * 4];
                acc[r].x = fmaf(ev.x, cx0.x, acc[r].x);
                acc[r].y = fmaf(ev.x, cx0.y, acc[r].y);
                acc[r].z = fmaf(ev.x, cx0.z, acc[r].z);
                acc[r].w = fmaf(ev.x, cx0.w, acc[r].w);
                acc[r].x = fmaf(ev.y, cx1.x, acc[r].x);
                acc[r].y = fmaf(ev.y, cx1.y, acc[r].y);
                acc[r].z = fmaf(ev.y, cx1.z, acc[r].z);
                acc[r].w = fmaf(ev.y, cx1.w, acc[r].w);
                acc[r].x = fmaf(ev.z, cx2.x, acc[r].x);
                acc[r].y = fmaf(ev.z, cx2.y, acc[r].y);
                acc[r].z = fmaf(ev.z, cx2.z, acc[r].z);
                acc[r].w = fmaf(ev.z, cx2.w, acc[r].w);
                acc[r].x = fmaf(ev.w, cx3.x, acc[r].x);
                acc[r].y = fmaf(ev.w, cx3.y, acc[r].y);
                acc[r].z = fmaf(ev.w, cx3.z, acc[r].z);
                acc[r].w = fmaf(ev.w, cx3.w, acc[r].w);
            }
        }

        // ---- scale by 1/denominator and write out ----
#pragma unroll
        for (int r = 0; r < 4; ++r) {
            const int row = rg4 + r;
            const float inv = 1.f / eq[row][128];
            float4 o;
            o.x = acc[r].x * inv; o.y = acc[r].y * inv;
            o.z = acc[r].z * inv; o.w = acc[r].w * inv;
            const int s = s_base + it * 64 + row;
            *(float4*)(out + ((size_t)b * NS + s) * HD + (size_t)h * ND + eg4) = o;
        }
    }
}

// ---------------------------------------------------------------------------
extern "C" void kernel_launch(void* const* d_in, const int* in_sizes, int n_in,
                              void* d_out, int out_size, void* d_ws, size_t ws_size,
                              hipStream_t stream) {
    (void)in_sizes; (void)n_in; (void)out_size;
    const float* q = (const float*)d_in[0];
    const float* k = (const float*)d_in[1];
    const float* v = (const float*)d_in[2];
    float* out = (float*)d_out;

    auto need = [](size_t nc) -> size_t {
        return 4ull * ((size_t)BH * nc * ND * ND +   // pctx
                       (size_t)BH * nc * ND +        // pden
                       (size_t)BH * ND * ND);        // ctx
    };
    const int nc = (ws_size >= need(4)) ? 4 : (ws_size >= need(2)) ? 2 : 1;

    float* pctx = (float*)d_ws;
    float* pden = pctx + (size_t)BH * nc * ND * ND;
    float* ctxp = pden + (size_t)BH * nc * ND;

    if (nc == 4)
        ctx_partial<4><<<BH * 4, 256, 0, stream>>>(k, v, pctx, pden);
    else if (nc == 2)
        ctx_partial<2><<<BH * 2, 256, 0, stream>>>(k, v, pctx, pden);
    else
        ctx_partial<1><<<BH * 1, 256, 0, stream>>>(k, v, pctx, pden);

    ctx_combine<<<(BH * ND * ND) / 256, 256, 0, stream>>>(pctx, pden, ctxp, nc);

    out_kernel<<<BH * 8, 512, 0, stream>>>(q, ctxp, out);
}

// Round 3
// 253.319 us; speedup vs baseline: 2.2310x; 2.2310x over previous
//
#include <hip/hip_runtime.h>

using bf16x8 = __attribute__((ext_vector_type(8))) short;
using f32x4  = __attribute__((ext_vector_type(4))) float;

static constexpr int NB = 8;
static constexpr int NS = 4096;
static constexpr int NH = 16;
static constexpr int ND = 128;
static constexpr int BH = NB * NH;   // 128
static constexpr int HD = NH * ND;   // 2048

// round-to-nearest-even pack of two fp32 -> bf16x2 in a uint32
__device__ inline unsigned pack2(float a, float b) {
    unsigned ua = __float_as_uint(a), ub = __float_as_uint(b);
    ua += 0x7fffu + ((ua >> 16) & 1u);
    ub += 0x7fffu + ((ub >> 16) & 1u);
    return (ua >> 16) | (ub & 0xffff0000u);
}

// ---------------------------------------------------------------------------
// Kernel 1: per (b,h,S-chunk): pctx_t[e][d] = sum_s exp(k[s,d]) * v[s,e]
// (written TRANSPOSED, fp32) + pden[d] = sum_s exp(k[s,d]).
// MFMA 16x16x32 bf16. LDS tiles [128 rows][64 s] bf16, XOR chunk-swizzled.
// 256 threads = 4 waves, each wave owns a 64x64 output quadrant.
// ---------------------------------------------------------------------------
template <int NC>
__global__ __launch_bounds__(256, 2)
void ctx_mfma(const float* __restrict__ kk, const float* __restrict__ vv,
              float* __restrict__ pctx_t, float* __restrict__ pden) {
    constexpr int SC = NS / NC;
    constexpr int T  = SC / 64;
    __shared__ __align__(16) unsigned short aL[2][128][64];  // exp(k)^T tiles
    __shared__ __align__(16) unsigned short bL[2][128][64];  // v^T tiles

    const int blk = blockIdx.x, bh = blk / NC, c = blk % NC;
    const int b = bh >> 4, h = bh & 15;
    const int tid = threadIdx.x, lane = tid & 63, wv = tid >> 6;
    const int r15 = lane & 15, hi = lane >> 4;
    const size_t base = (size_t)b * NS * HD + (size_t)h * ND;

    const int d  = tid & 127;        // row this thread stages (d for k, e for v)
    const int sh = tid >> 7;         // which 32-s half of the 64-s tile
    const float* kp0 = kk + base + d;
    const float* vp0 = vv + base + d;
    float dsum = 0.f;

    auto stage = [&](int t, int buf) {
        const size_t s0 = (size_t)(c * SC + t * 64 + 32 * sh);
        const float* kp = kp0 + s0 * HD;
        const float* vp = vp0 + s0 * HD;
#pragma unroll
        for (int g = 0; g < 4; ++g) {           // 8 consecutive s per group
            float kvv[8], vvv[8];
#pragma unroll
            for (int j = 0; j < 8; ++j) {
                kvv[j] = kp[(size_t)(g * 8 + j) * HD];
                vvv[j] = vp[(size_t)(g * 8 + j) * HD];
            }
            unsigned pk[4], pv[4];
#pragma unroll
            for (int j = 0; j < 4; ++j) {
                float e0 = __expf(kvv[2 * j]), e1 = __expf(kvv[2 * j + 1]);
                dsum += e0 + e1;
                pk[j] = pack2(e0, e1);
                pv[j] = pack2(vvv[2 * j], vvv[2 * j + 1]);
            }
            const int cs = 4 * sh + g;          // 16B chunk index along s
            const int cw = cs ^ (d & 7);        // XOR swizzle
            *(uint4*)&aL[buf][d][cw * 8] = make_uint4(pk[0], pk[1], pk[2], pk[3]);
            *(uint4*)&bL[buf][d][cw * 8] = make_uint4(pv[0], pv[1], pv[2], pv[3]);
        }
    };

    f32x4 acc[4][4];
#pragma unroll
    for (int m = 0; m < 4; ++m)
#pragma unroll
        for (int n = 0; n < 4; ++n) acc[m][n] = (f32x4){0.f, 0.f, 0.f, 0.f};

    const int wd = wv >> 1, we = wv & 1;        // wave's 64x64 quadrant

    stage(0, 0);
    for (int t = 0; t < T; ++t) {
        __syncthreads();                         // tile t staged & prev reads done
        if (t + 1 < T) stage(t + 1, (t + 1) & 1);
        const int buf = t & 1;
#pragma unroll
        for (int ks = 0; ks < 2; ++ks) {
            bf16x8 af[4], bfv[4];
#pragma unroll
            for (int m = 0; m < 4; ++m) {
                const int row = 64 * wd + 16 * m + r15;
                const int cw = (4 * ks + hi) ^ (row & 7);
                af[m] = *(const bf16x8*)&aL[buf][row][cw * 8];
            }
#pragma unroll
            for (int n = 0; n < 4; ++n) {
                const int row = 64 * we + 16 * n + r15;
                const int cw = (4 * ks + hi) ^ (row & 7);
                bfv[n] = *(const bf16x8*)&bL[buf][row][cw * 8];
            }
#pragma unroll
            for (int m = 0; m < 4; ++m)
#pragma unroll
                for (int n = 0; n < 4; ++n)
                    acc[m][n] = __builtin_amdgcn_mfma_f32_16x16x32_bf16(
                        af[m], bfv[n], acc[m][n], 0, 0, 0);
        }
    }

    // denominator partial: thread holds sum over its 32-s halves for column d
    __syncthreads();
    float* dr = (float*)&aL[0][0][0];
    dr[sh * 128 + d] = dsum;
    __syncthreads();
    if (tid < 128) pden[(size_t)blk * 128 + tid] = dr[tid] + dr[128 + tid];

    // write transposed partial context: pctx_t[e][d], float4 along d
    float* po = pctx_t + (size_t)blk * (ND * ND);
#pragma unroll
    for (int m = 0; m < 4; ++m)
#pragma unroll
        for (int n = 0; n < 4; ++n) {
            const int e  = 64 * we + 16 * n + r15;
            const int d0 = 64 * wd + 16 * m + 4 * hi;
            *(f32x4*)&po[e * ND + d0] = acc[m][n];
        }
}

// ---------------------------------------------------------------------------
// Kernel 2: sum chunk partials, normalize, emit bf16 ctx_t[e][d]
// ---------------------------------------------------------------------------
__global__ void ctx_combine(const float* __restrict__ pctx_t,
                            const float* __restrict__ pden,
                            unsigned short* __restrict__ ctx_t, int nc) {
    const int gid = blockIdx.x * 256 + threadIdx.x;      // over BH*16384/2
    const size_t w = (size_t)gid * 2;
    const int bh = (int)(w >> 14);
    const int wi = (int)(w & 16383);
    const int dd = wi & 127;
    float s0 = 0.f, s1 = 0.f, dn0 = 0.f, dn1 = 0.f;
    for (int c2 = 0; c2 < nc; ++c2) {
        const float* p  = pctx_t + (((size_t)(bh * nc + c2)) << 14) + wi;
        const float* pd = pden + (size_t)(bh * nc + c2) * ND + dd;
        s0 += p[0]; s1 += p[1];
        dn0 += pd[0]; dn1 += pd[1];
    }
    *(unsigned*)&ctx_t[w] = pack2(s0 / dn0, s1 / dn1);
}

// ---------------------------------------------------------------------------
// Kernel 3: out[s][e] = (1/sum_d exp(q[s,d])) * sum_d exp(q[s,d]) * ctx[d][e]
// A = exp(q) tiles (32 s x 128 d bf16, swizzled, double-buffered).
// B = ctx_t staged once in LDS; B-fragments hoisted to registers.
// 256 threads = 4 waves; wave w owns e-range [32w, 32w+32).
// ---------------------------------------------------------------------------
__global__ __launch_bounds__(256, 2)
void out_mfma(const float* __restrict__ qq,
              const unsigned short* __restrict__ ctx_t,
              float* __restrict__ out) {
    __shared__ __align__(16) unsigned short cL[128][128];    // 32KB ctx_t
    __shared__ __align__(16) unsigned short qL[2][32][128];  // 16KB q tiles
    __shared__ float qd[2][32];

    const int blk = blockIdx.x, bh = blk >> 3, c = blk & 7;
    const int b = bh >> 4, h = bh & 15;
    const int tid = threadIdx.x, lane = tid & 63, wv = tid >> 6;
    const int r15 = lane & 15, hi = lane >> 4;

    // stage ctx_t -> LDS (swizzled: chunk ^ (row&15))
    // 128 rows x 16 chunks = 2048 uint4; 256 threads x 8 = 2048  (R2 bug: was x4)
    {
        const unsigned short* src = ctx_t + ((size_t)bh << 14);
#pragma unroll
        for (int j = 0; j < 8; ++j) {
            const int g = tid + 256 * j;
            const int e = g >> 4, cs = g & 15;
            uint4 t4 = *(const uint4*)&src[e * 128 + cs * 8];
            *(uint4*)&cL[e][(cs ^ (e & 15)) * 8] = t4;
        }
    }

    const size_t qbase = (size_t)b * NS * HD + (size_t)h * ND;
    const int s_blk = c * 512;

    auto stageq = [&](int t, int buf) {
#pragma unroll
        for (int jj = 0; jj < 2; ++jj) {
            const int g = tid + 256 * jj;
            const int s = g >> 4, cs = g & 15;
            const float* qp = qq + qbase + (size_t)(s_blk + t * 32 + s) * HD + cs * 8;
            float x[8];
            *(float4*)&x[0] = *(const float4*)qp;
            *(float4*)&x[4] = *(const float4*)(qp + 4);
            float ps = 0.f;
            unsigned pw[4];
#pragma unroll
            for (int j2 = 0; j2 < 4; ++j2) {
                float e0 = __expf(x[2 * j2]), e1 = __expf(x[2 * j2 + 1]);
                ps += e0 + e1;
                pw[j2] = pack2(e0, e1);
            }
            ps += __shfl_xor(ps, 1);
            ps += __shfl_xor(ps, 2);
            ps += __shfl_xor(ps, 4);
            ps += __shfl_xor(ps, 8);            // row-sum across the 16 d-chunks
            *(uint4*)&qL[buf][s][(cs ^ (s & 15)) * 8] =
                make_uint4(pw[0], pw[1], pw[2], pw[3]);
            if ((lane & 15) == 0) qd[buf][s] = ps;
        }
    };

    __syncthreads();                             // ctx staged

    // hoist B fragments: wave w covers e in [32w, 32w+32)
    bf16x8 bfr[2][4];
#pragma unroll
    for (int n = 0; n < 2; ++n) {
        const int e = 32 * wv + 16 * n + r15;
#pragma unroll
        for (int ks = 0; ks < 4; ++ks) {
            const int cw = (4 * ks + hi) ^ (e & 15);
            bfr[n][ks] = *(const bf16x8*)&cL[e][cw * 8];
        }
    }

    stageq(0, 0);
    for (int t = 0; t < 16; ++t) {
        __syncthreads();
        if (t + 1 < 16) stageq(t + 1, (t + 1) & 1);
        const int buf = t & 1;

        f32x4 acc[2][2];
#pragma unroll
        for (int m = 0; m < 2; ++m)
#pragma unroll
            for (int n = 0; n < 2; ++n) acc[m][n] = (f32x4){0.f, 0.f, 0.f, 0.f};

#pragma unroll
        for (int ks = 0; ks < 4; ++ks) {
            bf16x8 af[2];
#pragma unroll
            for (int m = 0; m < 2; ++m) {
                const int s = 16 * m + r15;
                const int cw = (4 * ks + hi) ^ (s & 15);
                af[m] = *(const bf16x8*)&qL[buf][s][cw * 8];
            }
#pragma unroll
            for (int m = 0; m < 2; ++m)
#pragma unroll
                for (int n = 0; n < 2; ++n)
                    acc[m][n] = __builtin_amdgcn_mfma_f32_16x16x32_bf16(
                        af[m], bfr[n][ks], acc[m][n], 0, 0, 0);
        }

        // normalize + write
#pragma unroll
        for (int m = 0; m < 2; ++m) {
            const int sl0 = 16 * m + 4 * hi;
            const float i0 = 1.f / qd[buf][sl0];
            const float i1 = 1.f / qd[buf][sl0 + 1];
            const float i2 = 1.f / qd[buf][sl0 + 2];
            const float i3 = 1.f / qd[buf][sl0 + 3];
            const int srow = s_blk + t * 32 + sl0;
            float* ob = out + ((size_t)b * NS + srow) * HD + (size_t)h * ND;
#pragma unroll
            for (int n = 0; n < 2; ++n) {
                const int e = 32 * wv + 16 * n + r15;
                ob[0 * HD + e] = acc[m][n][0] * i0;
                ob[1 * HD + e] = acc[m][n][1] * i1;
                ob[2 * HD + e] = acc[m][n][2] * i2;
                ob[3 * HD + e] = acc[m][n][3] * i3;
            }
        }
    }
}

// ---------------------------------------------------------------------------
extern "C" void kernel_launch(void* const* d_in, const int* in_sizes, int n_in,
                              void* d_out, int out_size, void* d_ws, size_t ws_size,
                              hipStream_t stream) {
    (void)in_sizes; (void)n_in; (void)out_size;
    const float* q = (const float*)d_in[0];
    const float* k = (const float*)d_in[1];
    const float* v = (const float*)d_in[2];
    float* out = (float*)d_out;

    auto need = [](size_t nc) -> size_t {
        return 4ull * ((size_t)BH * nc * ND * ND + (size_t)BH * nc * ND) +
               2ull * (size_t)BH * ND * ND;
    };
    const int nc = (ws_size >= need(4)) ? 4 : (ws_size >= need(2)) ? 2 : 1;

    float* pctx_t = (float*)d_ws;
    float* pden   = pctx_t + (size_t)BH * nc * ND * ND;
    unsigned short* ctx_t = (unsigned short*)(pden + (size_t)BH * nc * ND);

    if (nc == 4)
        ctx_mfma<4><<<BH * 4, 256, 0, stream>>>(k, v, pctx_t, pden);
    else if (nc == 2)
        ctx_mfma<2><<<BH * 2, 256, 0, stream>>>(k, v, pctx_t, pden);
    else
        ctx_mfma<1><<<BH * 1, 256, 0, stream>>>(k, v, pctx_t, pden);

    ctx_combine<<<(BH * ND * ND / 2) / 256, 256, 0, stream>>>(pctx_t, pden, ctx_t, nc);

    out_mfma<<<BH * 8, 256, 0, stream>>>(q, ctx_t, out);
}